// Round 20
// baseline (231.126 us; speedup 1.0000x reference)
//
#include <hip/hip_runtime.h>
#include <stdint.h>

// ---------------------------------------------------------------------------
// EdgeNodeGCN on MI355X (gfx950). Inputs fp32, edge_index int32, output fp32.
// Factorization:
//   P[n]  = x[n] @ (Wa - Wb) + b_edge   (Wa = W_edge[0:128], Wb = W_edge[128:256])
//   Q[n]  = x[n] @ Wb
//   msg(e)= relu(P[dst] + Q[src]);  edge_agg[d] = sum msg
//   XA[d] = sum_{e->d} x[src]           (segment_sum commutes with @W_node)
//   nodes = relu(XA @ W_node + b_node); edges = relu(edge_agg @ W_ed + b_ed)
//   out   = sigmoid(relu([nodes|edges] @ W_f1 + b_f1) @ W_f2 + b_f2)
//
// R29 == R28 resubmit (R28 never ran: GPU acquisition timeout).
// R28 vs R27 (219.3 ~ R23 tie; stride fix neutral, conflicts hidden under
// fetch stalls): k_tailg = L2-miss-bound at 2.16 TB/s x 164MB ~= 76us, issue
// rate capped by 8 waves/CU (register pin: 152 weight VGPR + gather state
// ~256/wave -> 2 waves/SIMD). THE 8-WAVE WEIGHT SPLIT:
//   - 512-thr blocks, 8 waves; each wave owns 1/8 of weight cols:
//     bn[2][4]+be[8]+bfr[3] = 76 persistent VGPR (vs 152);
//   - gather = R22-validated half-wave-per-node (16 half-waves, 32 lanes,
//     2-way unroll, state ~40 VGPR); peak ~120 -> launch_bounds(512,4)
//     forces <=128 -> 4 waves/SIMD = 16 waves/CU (2x residency);
//   - h via SINGLE shared hs[16][392] in natural col order + 1 barrier;
//     Wf1 becomes plain transpose Wf1T (permutation deleted);
//   - MLP: wave w = (colgrp w>>2, Kslice w&3); red[8][16][17]; wave0 reduce.
//   - LDS 33.8KB -> 2 blocks/CU; grid 512 (tpb=7, R24 prologue lesson).
// Predicted: VGPR<=128 no scratch, Occ 16.6->~33%, hbm 2.16->~3.5 TB/s,
// k_tailg 80->~48-58, total -> ~185-197. If occ doubles but dur flat:
// fabric floor reached.
// Dispatches: convert, sg, tailg (3).
// ---------------------------------------------------------------------------

typedef short short8 __attribute__((ext_vector_type(8)));
typedef float f32x4 __attribute__((ext_vector_type(4)));
typedef float float4v __attribute__((ext_vector_type(4)));
typedef unsigned short us8 __attribute__((ext_vector_type(8)));
typedef unsigned short us4 __attribute__((ext_vector_type(4)));

__device__ inline float bf2f(unsigned short h) {
    union { unsigned int u; float f; } v;
    v.u = ((unsigned int)h) << 16;
    return v.f;
}
__device__ inline unsigned short f2bf(float f) {
    union { float f; unsigned int u; } v;
    v.f = f;
    unsigned int r = v.u + 0x7FFFu + ((v.u >> 16) & 1u);  // RNE
    return (unsigned short)(r >> 16);
}

// ---- convert x + weights -> bf16 (coalesced writes); head/deg init --------
__global__ __launch_bounds__(256) void k_convert(
    const float* __restrict__ x, const float* __restrict__ W_edge,
    const float* __restrict__ W_node, const float* __restrict__ W_ed,
    const float* __restrict__ W_f1,
    unsigned short* __restrict__ xb, unsigned short* __restrict__ WE2T,
    unsigned short* __restrict__ WnT, unsigned short* __restrict__ WdT,
    unsigned short* __restrict__ Wf1T, int* __restrict__ head,
    int* __restrict__ deg,
    int quads, int N)
{
    int i = blockIdx.x * 256 + threadIdx.x;
    if (i < quads) {
        float4v v = ((const float4v*)x)[i];
        us4 o;
        for (int j = 0; j < 4; ++j) o[j] = f2bf(v[j]);
        ((us4*)xb)[i] = o;
        return;
    }
    int j = i - quads;
    if (j < 65536) {                          // WE2T [512 c][128 k]: write elem j
        int c = j >> 7, k = j & 127;
        float v;
        if (c < 256) v = W_edge[k * 256 + c] - W_edge[(k + 128) * 256 + c];
        else         v = W_edge[(k + 128) * 256 + (c - 256)];
        WE2T[j] = f2bf(v);
    } else if (j < 65536 + 32768) {           // WnT [256 c][128 k]
        int t = j - 65536;
        int c = t >> 7, k = t & 127;
        WnT[t] = f2bf(W_node[k * 256 + c]);
    } else if (j < 65536 + 65536) {           // WdT [128 c][256 k]
        int t = j - 65536 - 32768;
        int c = t >> 8, k = t & 255;
        WdT[t] = f2bf(W_ed[k * 128 + c]);
    } else if (j < 143360) {                  // Wf1T [32 c][384 k] natural
        int t = j - 65536 - 65536;
        int c = t / 384, k = t - c * 384;
        Wf1T[t] = f2bf(W_f1[k * 32 + c]);
    } else {
        int t = j - 143360;
        if (t < N) { head[t] = -1; deg[t] = 0; }
    }
}

// ---- fused dispatch: padded-CSR build (1/3) + WIDE gemm (row-group/block) -
__global__ __launch_bounds__(512) void k_sg(
    const int* __restrict__ src, const int* __restrict__ dst,
    int* __restrict__ head, unsigned long long* __restrict__ next2,
    int* __restrict__ deg, int* __restrict__ adj,
    const unsigned short* __restrict__ xb,     // [N][128] bf16
    const unsigned short* __restrict__ WE2T,   // [512][128] bf16 col-major
    const float* __restrict__ b_edge,          // [256] fp32
    unsigned short* __restrict__ T,            // [N][512]
    int E, int N, int row_tiles, int scat_blocks, int gemm_blocks)
{
    __shared__ unsigned short st[2][16 * 524];
    int b = blockIdx.x;
    if (b % 3 == 2) {                          // scatter pass: padded CSR
        int sb_id = b / 3;
        if (sb_id >= scat_blocks) return;
        int i = sb_id * 512 + threadIdx.x;
        if (i >= E) return;
        int s = src[i], d = dst[i];
        if ((unsigned)d >= (unsigned)N || (unsigned)s >= (unsigned)N) return;
        int pos = atomicAdd(&deg[d], 1);
        if (pos < 32) {
            adj[(size_t)d * 32 + pos] = s;
        } else {                               // overflow: linked list
            int old = atomicExch(&head[d], i);
            next2[i] = ((unsigned long long)(unsigned)s << 32) | (unsigned)old;
        }
        return;
    }
    int g = b - b / 3;                         // gemm row-group id
    if (g >= gemm_blocks) return;

    const int lane = threadIdx.x & 63;
    const int wave = threadIdx.x >> 6;         // 0..7, owns cols [wave*64,+64)
    const int quad = lane >> 4;
    const int col16 = lane & 15;
    const int tid = threadIdx.x;

    // persistent B fragments: 4 col-chunks x 4 k-steps = 64 VGPR
    short8 bf[4][4];
    float bias[4];
#pragma unroll
    for (int cc = 0; cc < 4; ++cc) {
        int col = wave * 64 + cc * 16 + col16;
        bias[cc] = (col < 256) ? b_edge[col] : 0.f;
#pragma unroll
        for (int ks = 0; ks < 4; ++ks)
            bf[cc][ks] = *(const short8*)(WE2T + (size_t)col * 128 + ks * 32 + quad * 8);
    }

    int tmax = row_tiles - g * 8;              // block-uniform
    if (tmax > 8) tmax = 8;

    for (int t = 0; t < 8; ++t) {
        if (t >= tmax) break;                  // uniform: safe with barriers
        int r0 = (g * 8 + t) * 16;
        int arow = r0 + col16;
        if (arow >= N) arow = N - 1;

        // A-fragment: 4 loads feed 16 MFMAs
        short8 a[4];
        const unsigned short* ap = xb + (size_t)arow * 128 + quad * 8;
#pragma unroll
        for (int ks = 0; ks < 4; ++ks) a[ks] = *(const short8*)(ap + ks * 32);

        unsigned short* sbuf = st[t & 1];
#pragma unroll
        for (int cc = 0; cc < 4; ++cc) {
            f32x4 acc = {0.f, 0.f, 0.f, 0.f};
#pragma unroll
            for (int ks = 0; ks < 4; ++ks)
                acc = __builtin_amdgcn_mfma_f32_16x16x32_bf16(a[ks], bf[cc][ks], acc, 0, 0, 0);
#pragma unroll
            for (int r = 0; r < 4; ++r)
                sbuf[(quad * 4 + r) * 524 + wave * 64 + cc * 16 + col16] =
                    f2bf(acc[r] + bias[cc]);
        }

        __syncthreads();                       // one barrier per tile

        // store tile: 1024 us8-chunks, 512 threads x 2
#pragma unroll
        for (int p = 0; p < 2; ++p) {
            int chunk = tid + p * 512;
            int row = chunk >> 6;              // 0..15
            int cpos = (chunk & 63) * 8;       // 0..504
            if (r0 + row < N) {
                us8 v = *(const us8*)(sbuf + row * 524 + cpos);
                *(us8*)(T + (size_t)(r0 + row) * 512 + cpos) = v;
            }
        }
    }
}

// ---- Fused gather + tail, 8-wave weight split -----------------------------
// Gather: half-wave per node (16 half-waves = 16 nodes). h: single shared
// hs[16][392] natural order. MLP: wave w = (colgrp w>>2, Kslice w&3).
#define XES 392
#define HSS 392
__global__ __launch_bounds__(512, 4) void k_tailg(
    const unsigned short* __restrict__ T,    // [N][512] P|Q (read-only)
    const unsigned short* __restrict__ xb,   // [N][128]
    const int* __restrict__ deg,
    const int* __restrict__ adj,             // [N][32]
    const int* __restrict__ head,
    const unsigned long long* __restrict__ next2,
    const unsigned short* __restrict__ WnT,  // [256 c][128 k] col-major
    const unsigned short* __restrict__ WdT,  // [128 c][256 k] col-major
    const unsigned short* __restrict__ Wf1T, // [32 c][384 k] natural
    const float* __restrict__ b_node, const float* __restrict__ b_ed,
    const float* __restrict__ b_f1, const float* __restrict__ W_f2,
    const float* __restrict__ b_f2,
    float* __restrict__ out, int N, int row_tiles, int tiles_per_block)
{
    __shared__ unsigned short xe[16 * XES];   // XA(0-127)|EA(128-383) per tile
    __shared__ unsigned short hs[16 * HSS];   // h: nodes(0-255)|edges(256-383)
    __shared__ float red[8][16][17];          // MLP partials
    const int wave = threadIdx.x >> 6;        // 0..7
    const int lane = threadIdx.x & 63;
    const int quad = lane >> 4;
    const int col16 = lane & 15;

    // ---- persistent B fragments: 1/8 of weights per wave ----
    short8 bn[2][4], be[8], bfr[3];
    float bias_n[2], bias_e;
#pragma unroll
    for (int ci = 0; ci < 2; ++ci) {
        int col = (wave + ci * 8) * 16 + col16;        // node chunks w, w+8
        bias_n[ci] = b_node[col];
#pragma unroll
        for (int ks = 0; ks < 4; ++ks)
            bn[ci][ks] = *(const short8*)(WnT + (size_t)col * 128 + ks * 32 + quad * 8);
    }
    {
        int col = wave * 16 + col16;                   // edge chunk w
        bias_e = b_ed[col];
#pragma unroll
        for (int ks = 0; ks < 8; ++ks)
            be[ks] = *(const short8*)(WdT + (size_t)col * 256 + ks * 32 + quad * 8);
    }
    {
        int cg = wave >> 2, ksl = wave & 3;            // MLP colgrp, K-slice
        int c = cg * 16 + col16;
#pragma unroll
        for (int k3 = 0; k3 < 3; ++k3)
            bfr[k3] = *(const short8*)(Wf1T + (size_t)c * 384 + ksl * 96 + k3 * 32 + quad * 8);
    }

    int t0 = blockIdx.x * tiles_per_block;
    int t1 = t0 + tiles_per_block;
    if (t1 > row_tiles) t1 = row_tiles;

    for (int tile = t0; tile < t1; ++tile) {
        int r0 = tile * 16;

        // ============ gather phase: half-wave per node (R22 layout) ========
        {
            int half = lane >> 5;
            int c = lane & 31;
            int n = r0 + wave * 2 + half;
            bool act = n < N;
            int nn = act ? n : N - 1;
            int c8 = c * 8, c4 = c * 4;

            us8 pv = *(const us8*)(T + (size_t)nn * 512 + c8);
            float p[8];
#pragma unroll
            for (int j = 0; j < 8; ++j) p[j] = bf2f(pv[j]);
            float aE[8] = {0, 0, 0, 0, 0, 0, 0, 0};
            float aX[4] = {0, 0, 0, 0};

            int dg = act ? deg[n] : 0;
            int adjv = adj[(size_t)nn * 32 + c];
            int m = dg < 32 ? dg : 32;

            int k = 0;
            for (; k + 1 < m; k += 2) {        // 2-way unroll (validated)
                int s0 = __shfl(adjv, k, 32);
                int s1 = __shfl(adjv, k + 1, 32);
                us8 q0 = *(const us8*)(T + (size_t)s0 * 512 + 256 + c8);
                us8 q1 = *(const us8*)(T + (size_t)s1 * 512 + 256 + c8);
                us4 x0 = *(const us4*)(xb + (size_t)s0 * 128 + c4);
                us4 x1 = *(const us4*)(xb + (size_t)s1 * 128 + c4);
#pragma unroll
                for (int j = 0; j < 8; ++j) {
                    aE[j] += fmaxf(p[j] + bf2f(q0[j]), 0.f);
                    aE[j] += fmaxf(p[j] + bf2f(q1[j]), 0.f);
                }
#pragma unroll
                for (int j = 0; j < 4; ++j)
                    aX[j] += bf2f(x0[j]) + bf2f(x1[j]);
            }
            if (k < m) {
                int s0 = __shfl(adjv, k, 32);
                us8 q0 = *(const us8*)(T + (size_t)s0 * 512 + 256 + c8);
                us4 x0 = *(const us4*)(xb + (size_t)s0 * 128 + c4);
#pragma unroll
                for (int j = 0; j < 8; ++j) aE[j] += fmaxf(p[j] + bf2f(q0[j]), 0.f);
#pragma unroll
                for (int j = 0; j < 4; ++j) aX[j] += bf2f(x0[j]);
            }

            // overflow fallback (deg > 32): residual linked list
            int cur = (act && dg > 32) ? head[n] : -1;
            while (__any(cur >= 0)) {
                bool v = cur >= 0;
                int safe = v ? cur : 0;
                unsigned long long e2 = next2[safe];
                int s = (int)(e2 >> 32);
                float mm = v ? 1.f : 0.f;
                us8 qv = *(const us8*)(T + (size_t)s * 512 + 256 + c8);
                us4 xv = *(const us4*)(xb + (size_t)s * 128 + c4);
#pragma unroll
                for (int j = 0; j < 8; ++j)
                    aE[j] += mm * fmaxf(p[j] + bf2f(qv[j]), 0.f);
#pragma unroll
                for (int j = 0; j < 4; ++j)
                    aX[j] += mm * bf2f(xv[j]);
                cur = v ? (int)(unsigned)(e2 & 0xFFFFFFFFull) : -1;
            }

            // write xe row: XA cols [c*4,+4), EA cols 128+[c*8,+8)
            int qn = wave * 2 + half;
            unsigned short* xr = xe + qn * XES;
            us4 xo;
#pragma unroll
            for (int j = 0; j < 4; ++j) xo[j] = f2bf(aX[j]);
            *(us4*)(xr + c4) = xo;
            us8 eo;
#pragma unroll
            for (int j = 0; j < 8; ++j) eo[j] = f2bf(aE[j]);
            *(us8*)(xr + 128 + c8) = eo;
        }
        __syncthreads();   // xe complete

        // ============ h production: wave's 2 node chunks + 1 edge chunk ====
        {
            short8 ax[4];
#pragma unroll
            for (int ks = 0; ks < 4; ++ks)
                ax[ks] = *(const short8*)(xe + col16 * XES + ks * 32 + quad * 8);
#pragma unroll
            for (int ci = 0; ci < 2; ++ci) {
                int col = (wave + ci * 8) * 16 + col16;
                f32x4 acc = {0.f, 0.f, 0.f, 0.f};
#pragma unroll
                for (int ks = 0; ks < 4; ++ks)
                    acc = __builtin_amdgcn_mfma_f32_16x16x32_bf16(ax[ks], bn[ci][ks], acc, 0, 0, 0);
#pragma unroll
                for (int r = 0; r < 4; ++r)
                    hs[(quad * 4 + r) * HSS + col] = f2bf(fmaxf(acc[r] + bias_n[ci], 0.f));
            }

            short8 ae[8];
#pragma unroll
            for (int ks = 0; ks < 8; ++ks)
                ae[ks] = *(const short8*)(xe + col16 * XES + 128 + ks * 32 + quad * 8);
            {
                int col = 256 + wave * 16 + col16;
                f32x4 acc = {0.f, 0.f, 0.f, 0.f};
#pragma unroll
                for (int ks = 0; ks < 8; ++ks)
                    acc = __builtin_amdgcn_mfma_f32_16x16x32_bf16(ae[ks], be[ks], acc, 0, 0, 0);
#pragma unroll
                for (int r = 0; r < 4; ++r)
                    hs[(quad * 4 + r) * HSS + col] = f2bf(fmaxf(acc[r] + bias_e, 0.f));
            }
        }
        __syncthreads();   // hs complete

        // ============ MLP partial: colgrp cg over K-slice ksl*96 ===========
        {
            int ksl = wave & 3;
            f32x4 m = {0.f, 0.f, 0.f, 0.f};
#pragma unroll
            for (int k3 = 0; k3 < 3; ++k3) {
                short8 a = *(const short8*)(hs + col16 * HSS + ksl * 96 + k3 * 32 + quad * 8);
                m = __builtin_amdgcn_mfma_f32_16x16x32_bf16(a, bfr[k3], m, 0, 0, 0);
            }
#pragma unroll
            for (int r = 0; r < 4; ++r)
                red[wave][quad * 4 + r][col16] = m[r];
        }
        __syncthreads();

        // ============ final reduce + MLP2 + sigmoid on wave 0 ==============
        if (wave == 0) {
            int row = col16, g = quad;          // each lane: 8 cols of one row
            float s = 0.f;
#pragma unroll
            for (int cc = 0; cc < 8; ++cc) {
                int col = g * 8 + cc;
                int cg2 = col >> 4, cl = col & 15;
                float v = red[cg2 * 4 + 0][row][cl] + red[cg2 * 4 + 1][row][cl] +
                          red[cg2 * 4 + 2][row][cl] + red[cg2 * 4 + 3][row][cl] +
                          b_f1[col];
                s += fmaxf(v, 0.f) * W_f2[col];
            }
            s += __shfl_xor(s, 16, 64);
            s += __shfl_xor(s, 32, 64);
            if (g == 0 && r0 + row < N) {
                float v = s + b_f2[0];
                out[r0 + row] = 1.f / (1.f + __expf(-v));
            }
        }
        __syncthreads();   // xe/hs/red reused next tile
    }
}

extern "C" void kernel_launch(void* const* d_in, const int* in_sizes, int n_in,
                              void* d_out, int out_size, void* d_ws, size_t ws_size,
                              hipStream_t stream) {
    const float* x      = (const float*)d_in[0];
    const int*   ei     = (const int*)d_in[1];
    // d_in[2] = e (unused)
    const float* W_node = (const float*)d_in[3];
    const float* b_node = (const float*)d_in[4];
    const float* W_edge = (const float*)d_in[5];
    const float* b_edge = (const float*)d_in[6];
    const float* W_ed   = (const float*)d_in[7];
    const float* b_ed   = (const float*)d_in[8];
    const float* W_f1   = (const float*)d_in[9];
    const float* b_f1   = (const float*)d_in[10];
    const float* W_f2   = (const float*)d_in[11];
    const float* b_f2   = (const float*)d_in[12];

    const int N = in_sizes[0] / 128;
    const int E = in_sizes[1] / 2;
    const int* src = ei;
    const int* dst = ei + E;

    char* ws = (char*)d_ws;
    size_t off = 0;
    auto alloc = [&](size_t bytes) { size_t o = off; off += (bytes + 255) & ~(size_t)255; return o; };
    unsigned short* xb   = (unsigned short*)(ws + alloc((size_t)N * 128 * 2));
    unsigned short* WE2T = (unsigned short*)(ws + alloc(512 * 128 * 2));
    unsigned short* WnT  = (unsigned short*)(ws + alloc(256 * 128 * 2));
    unsigned short* WdT  = (unsigned short*)(ws + alloc(128 * 256 * 2));
    unsigned short* Wf1T = (unsigned short*)(ws + alloc(32 * 384 * 2));
    unsigned short* T    = (unsigned short*)(ws + alloc((size_t)N * 512 * 2));
    int* head            = (int*)(ws + alloc((size_t)N * 4));
    unsigned long long* next2 = (unsigned long long*)(ws + alloc((size_t)E * 8));
    int* deg             = (int*)(ws + alloc((size_t)N * 4));
    int* adj             = (int*)(ws + alloc((size_t)N * 32 * 4));

    const int row_tiles   = (N + 15) / 16;
    const int row_groups  = (row_tiles + 7) / 8;
    const int quads       = N * 128 / 4;
    const int conv_items  = quads + 143360 + N;
    const int scat_blocks = (E + 511) / 512;
    const int gemm_blocks = row_groups;            // wide blocks: 1 per group
    int grid3 = scat_blocks * 3;
    int need_g = ((gemm_blocks + 1) / 2) * 3;
    if (need_g > grid3) grid3 = need_g;

    k_convert<<<(conv_items + 255) / 256, 256, 0, stream>>>(
        x, W_edge, W_node, W_ed, W_f1, xb, WE2T, WnT, WdT, Wf1T, head, deg,
        quads, N);
    k_sg<<<grid3, 512, 0, stream>>>(
        src, dst, head, next2, deg, adj, xb, WE2T, b_edge, T, E, N, row_tiles,
        scat_blocks, gemm_blocks);

    // 512 blocks (2/CU at 8 waves): amortizes weight prologue over ~7 tiles
    int tail_blocks = 512;
    if (tail_blocks > row_tiles) tail_blocks = row_tiles;
    int tpb = (row_tiles + tail_blocks - 1) / tail_blocks;
    k_tailg<<<tail_blocks, 512, 0, stream>>>(
        T, xb, deg, adj, head, next2, WnT, WdT, Wf1T,
        b_node, b_ed, b_f1, W_f2, b_f2,
        (float*)d_out, N, row_tiles, tpb);
}